// Round 3
// baseline (229.662 us; speedup 1.0000x reference)
//
#include <hip/hip_runtime.h>
#include <stdint.h>
#include <math.h>

#define BB 2
#define SS 2048
#define DDIM 512
#define HH 8
#define HDD 64
static constexpr float SCALE = 0.125f; // 64^-0.5

typedef unsigned short u16;
typedef short bf16x8 __attribute__((ext_vector_type(8)));
typedef float f32x4 __attribute__((ext_vector_type(4)));

__device__ __forceinline__ u16 f2bf(float x) {
  unsigned int u = __float_as_uint(x);
  unsigned int r = (u + 0x7fffu + ((u >> 16) & 1u)) >> 16; // RNE
  return (u16)r;
}

// async global->LDS, 16B per lane. LDS dest must be wave-uniform base + lane*16.
// NOTE: direct C-style casts => clang addrspacecast (generic->AS1 / generic->AS3).
__device__ __forceinline__ void cp16(const void* g, void* l) {
  __builtin_amdgcn_global_load_lds(
      (const __attribute__((address_space(1))) void*)g,
      (__attribute__((address_space(3))) void*)l, 16, 0, 0);
}

// ---------------- cast gene/expr fp32 -> bf16 ----------------
__global__ __launch_bounds__(256) void cast_bf16_k(
    const float* __restrict__ g, const float* __restrict__ e,
    u16* __restrict__ og, u16* __restrict__ oe) {
  int i = blockIdx.x * 256 + threadIdx.x; // 524288 threads, 1 float4 each
  float4 a = ((const float4*)g)[i];
  float4 b = ((const float4*)e)[i];
  ushort4 ua, ub;
  ua.x = f2bf(a.x); ua.y = f2bf(a.y); ua.z = f2bf(a.z); ua.w = f2bf(a.w);
  ub.x = f2bf(b.x); ub.y = f2bf(b.y); ub.z = f2bf(b.z); ub.w = f2bf(b.w);
  ((ushort4*)og)[i] = ua;
  ((ushort4*)oe)[i] = ub;
}

// ---------------- transpose + cast weights: W[K][512] -> WT[512][K] bf16 ----------------
__global__ __launch_bounds__(256) void wprep_k(
    const float* __restrict__ Wf, const float* __restrict__ Wq,
    const float* __restrict__ Wk, const float* __restrict__ Wv,
    const float* __restrict__ Wo,
    u16* __restrict__ WfT, u16* __restrict__ WqT, u16* __restrict__ WkT,
    u16* __restrict__ WvT, u16* __restrict__ WoT) {
  int z = blockIdx.z;
  const float* W; u16* WT; int K;
  switch (z) {
    case 0: W = Wf; WT = WfT; K = 1024; break;
    case 1: W = Wq; WT = WqT; K = 512; break;
    case 2: W = Wk; WT = WkT; K = 512; break;
    case 3: W = Wv; WT = WvT; K = 512; break;
    default: W = Wo; WT = WoT; K = 512; break;
  }
  int k0 = blockIdx.y * 32;
  if (k0 >= K) return;
  int n0 = blockIdx.x * 32;
  __shared__ float t[32][33];
  int tx = threadIdx.x & 31, ty = threadIdx.x >> 5;
#pragma unroll
  for (int i = 0; i < 32; i += 8)
    t[ty + i][tx] = W[(size_t)(k0 + ty + i) * DDIM + n0 + tx];
  __syncthreads();
#pragma unroll
  for (int i = 0; i < 32; i += 8)
    WT[(size_t)(n0 + ty + i) * K + k0 + tx] = f2bf(t[tx][ty + i]);
}

// ---------------- bf16 MFMA GEMM, m97-style 2-barrier loop ----------------
// C[M=4096][N=512] = A[M][K] @ Bt[N][K]^T + bias
// EPI 0: A = concat(gene,expr) k-split, K=1024, out bf16 row-major (fused)
// EPI 1: z = blockIdx.z: 0->Q (B,H,S,HD), 1->K (B,H,S,HD), 2->V transposed (B,H,HD,S)
// EPI 2: out fp32 row-major (final projection)
template <int EPI>
__global__ __launch_bounds__(256) void gemm_k(
    const u16* __restrict__ A0, const u16* __restrict__ A1,
    const u16* __restrict__ Bt0, const u16* __restrict__ Bt1,
    const u16* __restrict__ Bt2,
    const float* __restrict__ bias0, const float* __restrict__ bias1,
    const float* __restrict__ bias2,
    u16* __restrict__ O0, u16* __restrict__ O1, u16* __restrict__ O2,
    float* __restrict__ OF) {
  constexpr int BK = 32;
  __shared__ alignas(16) u16 Al[128 * BK];
  __shared__ alignas(16) u16 Bl[64 * BK];

  const int tid = threadIdx.x;
  const int l = tid & 63, w = tid >> 6, lg = l >> 4, lr = l & 15;
  const int wm = w >> 1, wn = w & 1;
  const int m0 = blockIdx.y * 128;
  const int n0 = blockIdx.x * 64;
  const int Ksz = (EPI == 0) ? 1024 : 512;

  const u16* Aa = A0; const u16* Bt = Bt0; const float* bias = bias0;
  int z = 0;
  if (EPI == 1) {
    z = blockIdx.z;
    Aa = (z == 2) ? A1 : A0;
    Bt = (z == 0) ? Bt0 : (z == 1) ? Bt1 : Bt2;
    bias = (z == 0) ? bias0 : (z == 1) ? bias1 : bias2;
  }

  f32x4 zero4 = {0.f, 0.f, 0.f, 0.f};
  f32x4 acc[4][2];
#pragma unroll
  for (int i = 0; i < 4; ++i)
#pragma unroll
    for (int j = 0; j < 2; ++j) acc[i][j] = zero4;

  const int arow = tid >> 2; // 0..63
  const int apos = tid & 3;  // 16B chunk within 64B row

  for (int k0 = 0; k0 < Ksz; k0 += BK) {
    __syncthreads();
    // stage A: 128x32 bf16 (8KB), 2 chunks/thread; swizzled source, linear dest
#pragma unroll
    for (int c = 0; c < 2; ++c) {
      int row = arow + 64 * c;
      int k8 = apos ^ ((row >> 1) & 3);
      int kg = k0 + 8 * k8;
      const u16* src;
      if (EPI == 0) {
        src = (kg < 512) ? (A0 + (size_t)(m0 + row) * 512 + kg)
                         : (A1 + (size_t)(m0 + row) * 512 + (kg - 512));
      } else {
        src = Aa + (size_t)(m0 + row) * 512 + kg;
      }
      cp16(src, (char*)Al + (size_t)row * 64 + apos * 16);
    }
    // stage B: 64x32 bf16 (4KB), 1 chunk/thread
    {
      int row = arow;
      int k8 = apos ^ ((row >> 1) & 3);
      const u16* src = Bt + (size_t)(n0 + row) * Ksz + k0 + 8 * k8;
      cp16(src, (char*)Bl + (size_t)row * 64 + apos * 16);
    }
    asm volatile("s_waitcnt vmcnt(0)" ::: "memory");
    __syncthreads();

    bf16x8 af[4], bfr[2];
#pragma unroll
    for (int i = 0; i < 4; ++i) {
      int row = 64 * wm + 16 * i + lr;
      af[i] = *(const bf16x8*)((const char*)Al + row * 64 +
                               ((lg ^ ((row >> 1) & 3)) * 16));
    }
#pragma unroll
    for (int j = 0; j < 2; ++j) {
      int row = 32 * wn + 16 * j + lr;
      bfr[j] = *(const bf16x8*)((const char*)Bl + row * 64 +
                                ((lg ^ ((row >> 1) & 3)) * 16));
    }
#pragma unroll
    for (int i = 0; i < 4; ++i)
#pragma unroll
      for (int j = 0; j < 2; ++j)
        acc[i][j] =
            __builtin_amdgcn_mfma_f32_16x16x32_bf16(af[i], bfr[j], acc[i][j], 0, 0, 0);
  }

  // epilogue: D row = 4*lg + r, col = lr (per 16x16 tile)
#pragma unroll
  for (int j = 0; j < 2; ++j) {
    int c = n0 + 32 * wn + 16 * j + lr;
    float bv = bias[c];
#pragma unroll
    for (int i = 0; i < 4; ++i) {
      int qb = m0 + 64 * wm + 16 * i + 4 * lg; // row for r=0
      if (EPI == 0) {
#pragma unroll
        for (int r = 0; r < 4; ++r)
          O0[(size_t)(qb + r) * 512 + c] = f2bf(acc[i][j][r] + bv);
      } else if (EPI == 2) {
#pragma unroll
        for (int r = 0; r < 4; ++r)
          OF[(size_t)(qb + r) * 512 + c] = acc[i][j][r] + bv;
      } else {
        int b = qb >> 11, s = qb & 2047;
        int hh = c >> 6, hd = c & 63;
        if (z < 2) {
          u16* O = (z == 0) ? O0 : O1;
#pragma unroll
          for (int r = 0; r < 4; ++r)
            O[((size_t)(b * HH + hh) * SS + s + r) * HDD + hd] =
                f2bf(acc[i][j][r] + bv);
        } else {
          ushort4 v;
          v.x = f2bf(acc[i][j][0] + bv);
          v.y = f2bf(acc[i][j][1] + bv);
          v.z = f2bf(acc[i][j][2] + bv);
          v.w = f2bf(acc[i][j][3] + bv);
          *(ushort4*)(O2 + ((size_t)(b * HH + hh) * HDD + hd) * SS + s) = v;
        }
      }
    }
  }
}

// ---------------- flash attention with exact masked softmax ----------------
// grid (32 qtiles, 16 bh). 4 waves x 16 q-rows. K/V tiles 64x64 bf16 in LDS,
// XOR-swizzled (pos = k8 ^ (row&7)) both sides; P bounced via per-wave LDS.
__global__ __launch_bounds__(256) void attn_k(
    const u16* __restrict__ Qh, const u16* __restrict__ Kh,
    const u16* __restrict__ Vt, const float* __restrict__ Mm,
    u16* __restrict__ AO) {
  __shared__ alignas(16) u16 Kl[64 * 64];
  __shared__ alignas(16) u16 Vl[64 * 64];
  __shared__ alignas(16) u16 Pl[4][16 * 64];

  const int tid = threadIdx.x;
  const int l = tid & 63, w = tid >> 6, lg = l >> 4, lr = l & 15;
  const int bh = blockIdx.y, b = bh >> 3, h = bh & 7;
  const int qw = blockIdx.x * 64 + 16 * w;

  // Q fragments held in registers for the whole kernel (A-frag: row=lr, k=8*lg+j)
  bf16x8 qf[2];
  {
    const u16* qp = Qh + ((size_t)bh * SS + qw + lr) * HDD + 8 * lg;
    qf[0] = *(const bf16x8*)qp;
    qf[1] = *(const bf16x8*)(qp + 32);
  }
  f32x4 zero4 = {0.f, 0.f, 0.f, 0.f};
  f32x4 o[4];
#pragma unroll
  for (int t = 0; t < 4; ++t) o[t] = zero4;
  float mrun[4] = {-INFINITY, -INFINITY, -INFINITY, -INFINITY};
  float lrun[4] = {0.f, 0.f, 0.f, 0.f};

  const float* Mb = Mm + ((size_t)b * SS + qw + 4 * lg) * SS;

  const int srow = tid >> 3; // staging: off = tid*16 + c*4096 -> row = tid/8 + 32c
  const int spos = tid & 7;

  for (int kt = 0; kt < SS / 64; ++kt) {
    const int kb = kt * 64;
    __syncthreads();
#pragma unroll
    for (int c = 0; c < 2; ++c) {
      int row = srow + 32 * c;
      int k8 = spos ^ (row & 7);
      size_t off = (size_t)tid * 16 + (size_t)c * 4096;
      cp16(Kh + ((size_t)bh * SS + kb + row) * HDD + 8 * k8, (char*)Kl + off);
      cp16(Vt + ((size_t)bh * HDD + row) * SS + kb + 8 * k8, (char*)Vl + off);
    }
    asm volatile("s_waitcnt vmcnt(0)" ::: "memory");
    __syncthreads();

    // QK^T: sc[ct] rows 4lg+r, cols 16ct+lr
    f32x4 sc[4];
#pragma unroll
    for (int ct = 0; ct < 4; ++ct) {
      int krow = 16 * ct + lr;
      const char* kbase = (const char*)Kl + krow * 128;
      bf16x8 k0f = *(const bf16x8*)(kbase + ((lg) ^ (krow & 7)) * 16);
      bf16x8 k1f = *(const bf16x8*)(kbase + ((4 + lg) ^ (krow & 7)) * 16);
      f32x4 zz = zero4;
      zz = __builtin_amdgcn_mfma_f32_16x16x32_bf16(qf[0], k0f, zz, 0, 0, 0);
      zz = __builtin_amdgcn_mfma_f32_16x16x32_bf16(qf[1], k1f, zz, 0, 0, 0);
      sc[ct] = zz;
    }
    // scale + mask (masked softmax == reference's softmax*M renormalized)
#pragma unroll
    for (int ct = 0; ct < 4; ++ct) {
#pragma unroll
      for (int r = 0; r < 4; ++r) {
        float mv = Mb[(size_t)r * SS + kb + 16 * ct + lr];
        sc[ct][r] = (mv != 0.0f) ? sc[ct][r] * SCALE : -INFINITY;
      }
    }
    // online softmax, per accumulator row r (rows 4lg+r; reduce across lr lanes)
#pragma unroll
    for (int r = 0; r < 4; ++r) {
      float t = fmaxf(fmaxf(sc[0][r], sc[1][r]), fmaxf(sc[2][r], sc[3][r]));
      t = fmaxf(t, __shfl_xor(t, 1));
      t = fmaxf(t, __shfl_xor(t, 2));
      t = fmaxf(t, __shfl_xor(t, 4));
      t = fmaxf(t, __shfl_xor(t, 8));
      float mnew = fmaxf(mrun[r], t);
      float fac = (mnew == -INFINITY) ? 1.0f : __expf(mrun[r] - mnew);
      float psum = 0.f;
#pragma unroll
      for (int ct = 0; ct < 4; ++ct) {
        float p = (sc[ct][r] == -INFINITY) ? 0.f : __expf(sc[ct][r] - mnew);
        sc[ct][r] = p;
        psum += p;
      }
      psum += __shfl_xor(psum, 1);
      psum += __shfl_xor(psum, 2);
      psum += __shfl_xor(psum, 4);
      psum += __shfl_xor(psum, 8);
      mrun[r] = mnew;
      lrun[r] = lrun[r] * fac + psum;
#pragma unroll
      for (int t4 = 0; t4 < 4; ++t4) o[t4][r] *= fac;
    }
    // P -> per-wave LDS (bf16, swizzled), then PV
    u16* Pw = Pl[w];
#pragma unroll
    for (int ct = 0; ct < 4; ++ct) {
#pragma unroll
      for (int r = 0; r < 4; ++r) {
        int row = 4 * lg + r;
        int col = 16 * ct + lr;
        int pos = (col >> 3) ^ (row & 7);
        Pw[row * 64 + pos * 8 + (col & 7)] = f2bf(sc[ct][r]);
      }
    }
#pragma unroll
    for (int kk = 0; kk < 2; ++kk) {
      bf16x8 pf = *(const bf16x8*)((const char*)Pw + lr * 128 +
                                   (((4 * kk + lg) ^ (lr & 7)) * 16));
#pragma unroll
      for (int t4 = 0; t4 < 4; ++t4) {
        int vrow = 16 * t4 + lr;
        bf16x8 vf = *(const bf16x8*)((const char*)Vl + vrow * 128 +
                                     (((4 * kk + lg) ^ (vrow & 7)) * 16));
        o[t4] = __builtin_amdgcn_mfma_f32_16x16x32_bf16(pf, vf, o[t4], 0, 0, 0);
      }
    }
  }

  // epilogue: divide by masked row-sum, store bf16 (B,S,D)
#pragma unroll
  for (int r = 0; r < 4; ++r) {
    float inv = (lrun[r] > 0.f) ? 1.0f / (lrun[r] + 1e-8f) : 0.f;
    size_t row = (size_t)b * SS + qw + 4 * lg + r;
#pragma unroll
    for (int t4 = 0; t4 < 4; ++t4) {
      int d = 16 * t4 + lr;
      AO[row * DDIM + h * HDD + d] = f2bf(o[t4][r] * inv);
    }
  }
}

// ---------------- launcher ----------------
extern "C" void kernel_launch(void* const* d_in, const int* in_sizes, int n_in,
                              void* d_out, int out_size, void* d_ws, size_t ws_size,
                              hipStream_t stream) {
  // workspace budget: 7*4MB (activations) + 1MB + 4*512KB (weights) = 31MB.
  // If the harness gave us less, bail out cleanly (diagnostic: output stays
  // poisoned -> "incorrect", NOT a container crash).
  if (ws_size < (size_t)(31.5 * 1024 * 1024)) return;

  const float* gene = (const float*)d_in[0];
  const float* expr = (const float*)d_in[1];
  const float* Mm = (const float*)d_in[2];
  const float* Wf = (const float*)d_in[3];
  const float* bf = (const float*)d_in[4];
  const float* Wq = (const float*)d_in[5];
  const float* bq = (const float*)d_in[6];
  const float* Wk = (const float*)d_in[7];
  const float* bk = (const float*)d_in[8];
  const float* Wv = (const float*)d_in[9];
  const float* bv = (const float*)d_in[10];
  const float* Wo = (const float*)d_in[11];
  const float* bo = (const float*)d_in[12];
  float* out = (float*)d_out;

  char* ws = (char*)d_ws;
  const size_t MB4 = 4194304; // 4096*512*2 bytes
  u16* geneB = (u16*)(ws + 0 * MB4);
  u16* exprB = (u16*)(ws + 1 * MB4);
  u16* fusedB = (u16*)(ws + 2 * MB4);
  u16* QhB = (u16*)(ws + 3 * MB4);
  u16* KhB = (u16*)(ws + 4 * MB4);
  u16* VtB = (u16*)(ws + 5 * MB4);
  u16* attnB = (u16*)(ws + 6 * MB4);
  u16* WfT = (u16*)(ws + 7 * MB4);
  u16* WqT = (u16*)(ws + 7 * MB4 + 1048576);
  u16* WkT = (u16*)(ws + 7 * MB4 + 1048576 + 524288);
  u16* WvT = (u16*)(ws + 7 * MB4 + 1048576 + 2 * 524288);
  u16* WoT = (u16*)(ws + 7 * MB4 + 1048576 + 3 * 524288);

  cast_bf16_k<<<2048, 256, 0, stream>>>(gene, expr, geneB, exprB);
  wprep_k<<<dim3(16, 32, 5), 256, 0, stream>>>(Wf, Wq, Wk, Wv, Wo, WfT, WqT,
                                               WkT, WvT, WoT);
  gemm_k<0><<<dim3(8, 32), 256, 0, stream>>>(geneB, exprB, WfT, nullptr, nullptr,
                                             bf, nullptr, nullptr, fusedB,
                                             nullptr, nullptr, nullptr);
  gemm_k<1><<<dim3(8, 32, 3), 256, 0, stream>>>(fusedB, exprB, WqT, WkT, WvT,
                                                bq, bk, bv, QhB, KhB, VtB,
                                                nullptr);
  attn_k<<<dim3(32, 16), 256, 0, stream>>>(QhB, KhB, VtB, Mm, attnB);
  gemm_k<2><<<dim3(8, 32), 256, 0, stream>>>(attnB, nullptr, WoT, nullptr,
                                             nullptr, bo, nullptr, nullptr,
                                             nullptr, nullptr, nullptr, out);
}

// Round 4
// 225.151 us; speedup vs baseline: 1.0200x; 1.0200x over previous
//
#include <hip/hip_runtime.h>
#include <stdint.h>
#include <math.h>

#define BB 2
#define SS 2048
#define DDIM 512
#define HH 8
#define HDD 64
static constexpr float SCALE = 0.125f; // 64^-0.5

typedef unsigned short u16;
typedef short bf16x8 __attribute__((ext_vector_type(8)));
typedef float f32x4 __attribute__((ext_vector_type(4)));

__device__ __forceinline__ u16 f2bf(float x) {
  unsigned int u = __float_as_uint(x);
  unsigned int r = (u + 0x7fffu + ((u >> 16) & 1u)) >> 16; // RNE
  return (u16)r;
}

// async global->LDS, 16B per lane. LDS dest must be wave-uniform base + lane*16.
__device__ __forceinline__ void cp16(const void* g, void* l) {
  __builtin_amdgcn_global_load_lds(
      (const __attribute__((address_space(1))) void*)g,
      (__attribute__((address_space(3))) void*)l, 16, 0, 0);
}

// ---------------- cast gene/expr fp32 -> bf16 ----------------
__global__ __launch_bounds__(256) void cast_bf16_k(
    const float* __restrict__ g, const float* __restrict__ e,
    u16* __restrict__ og, u16* __restrict__ oe) {
  int i = blockIdx.x * 256 + threadIdx.x;
  float4 a = ((const float4*)g)[i];
  float4 b = ((const float4*)e)[i];
  ushort4 ua, ub;
  ua.x = f2bf(a.x); ua.y = f2bf(a.y); ua.z = f2bf(a.z); ua.w = f2bf(a.w);
  ub.x = f2bf(b.x); ub.y = f2bf(b.y); ub.z = f2bf(b.z); ub.w = f2bf(b.w);
  ((ushort4*)og)[i] = ua;
  ((ushort4*)oe)[i] = ub;
}

// ---------------- transpose + cast weights: W[K][512] -> WT[512][K] bf16 ----------------
__global__ __launch_bounds__(256) void wprep_k(
    const float* __restrict__ Wf, const float* __restrict__ Wq,
    const float* __restrict__ Wk, const float* __restrict__ Wv,
    const float* __restrict__ Wo,
    u16* __restrict__ WfT, u16* __restrict__ WqT, u16* __restrict__ WkT,
    u16* __restrict__ WvT, u16* __restrict__ WoT) {
  int z = blockIdx.z;
  const float* W; u16* WT; int K;
  switch (z) {
    case 0: W = Wf; WT = WfT; K = 1024; break;
    case 1: W = Wq; WT = WqT; K = 512; break;
    case 2: W = Wk; WT = WkT; K = 512; break;
    case 3: W = Wv; WT = WvT; K = 512; break;
    default: W = Wo; WT = WoT; K = 512; break;
  }
  int k0 = blockIdx.y * 32;
  if (k0 >= K) return;
  int n0 = blockIdx.x * 32;
  __shared__ float t[32][33];
  int tx = threadIdx.x & 31, ty = threadIdx.x >> 5;
#pragma unroll
  for (int i = 0; i < 32; i += 8)
    t[ty + i][tx] = W[(size_t)(k0 + ty + i) * DDIM + n0 + tx];
  __syncthreads();
#pragma unroll
  for (int i = 0; i < 32; i += 8)
    WT[(size_t)(n0 + ty + i) * K + k0 + tx] = f2bf(t[tx][ty + i]);
}

// ---------------- bf16 MFMA GEMM, 64x64 tile (2 blocks+/CU for overlap) -----
// C[M=4096][N=512] = A[M][K] @ Bt[N][K]^T + bias
// EPI 0: A = concat(gene,expr) k-split, K=1024, out bf16 row-major (fused)
// EPI 1: z: 0->Q (B,H,S,HD), 1->K (B,H,S,HD), 2->V transposed (B,H,HD,S)
// EPI 2: out fp32 row-major (final projection)
template <int EPI>
__global__ __launch_bounds__(256) void gemm_k(
    const u16* __restrict__ A0, const u16* __restrict__ A1,
    const u16* __restrict__ Bt0, const u16* __restrict__ Bt1,
    const u16* __restrict__ Bt2,
    const float* __restrict__ bias0, const float* __restrict__ bias1,
    const float* __restrict__ bias2,
    u16* __restrict__ O0, u16* __restrict__ O1, u16* __restrict__ O2,
    float* __restrict__ OF) {
  constexpr int BK = 32;
  __shared__ alignas(16) u16 Al[64 * BK];
  __shared__ alignas(16) u16 Bl[64 * BK];

  const int tid = threadIdx.x;
  const int l = tid & 63, w = tid >> 6, lg = l >> 4, lr = l & 15;
  const int wm = w >> 1, wn = w & 1;
  const int m0 = blockIdx.y * 64;
  const int n0 = blockIdx.x * 64;
  const int Ksz = (EPI == 0) ? 1024 : 512;

  const u16* Aa = A0; const u16* Bt = Bt0; const float* bias = bias0;
  int z = 0;
  if (EPI == 1) {
    z = blockIdx.z;
    Aa = (z == 2) ? A1 : A0;
    Bt = (z == 0) ? Bt0 : (z == 1) ? Bt1 : Bt2;
    bias = (z == 0) ? bias0 : (z == 1) ? bias1 : bias2;
  }

  f32x4 zero4 = {0.f, 0.f, 0.f, 0.f};
  f32x4 acc[2][2];
#pragma unroll
  for (int i = 0; i < 2; ++i)
#pragma unroll
    for (int j = 0; j < 2; ++j) acc[i][j] = zero4;

  const int arow = tid >> 2; // 0..63
  const int apos = tid & 3;  // 16B chunk within 64B row
  const int k8s = apos ^ ((arow >> 1) & 3);

  for (int k0 = 0; k0 < Ksz; k0 += BK) {
    __syncthreads();
    // stage A: 64x32 bf16 (4KB), 1 chunk/thread; swizzled source, linear dest
    {
      int kg = k0 + 8 * k8s;
      const u16* src;
      if (EPI == 0) {
        src = (kg < 512) ? (A0 + (size_t)(m0 + arow) * 512 + kg)
                         : (A1 + (size_t)(m0 + arow) * 512 + (kg - 512));
      } else {
        src = Aa + (size_t)(m0 + arow) * 512 + kg;
      }
      cp16(src, (char*)Al + (size_t)arow * 64 + apos * 16);
    }
    // stage B: 64x32 bf16 (4KB), 1 chunk/thread
    {
      const u16* src = Bt + (size_t)(n0 + arow) * Ksz + k0 + 8 * k8s;
      cp16(src, (char*)Bl + (size_t)arow * 64 + apos * 16);
    }
    asm volatile("s_waitcnt vmcnt(0)" ::: "memory");
    __syncthreads();

    bf16x8 af[2], bfr[2];
#pragma unroll
    for (int i = 0; i < 2; ++i) {
      int row = 32 * wm + 16 * i + lr;
      af[i] = *(const bf16x8*)((const char*)Al + row * 64 +
                               ((lg ^ ((row >> 1) & 3)) * 16));
    }
#pragma unroll
    for (int j = 0; j < 2; ++j) {
      int row = 32 * wn + 16 * j + lr;
      bfr[j] = *(const bf16x8*)((const char*)Bl + row * 64 +
                                ((lg ^ ((row >> 1) & 3)) * 16));
    }
#pragma unroll
    for (int i = 0; i < 2; ++i)
#pragma unroll
      for (int j = 0; j < 2; ++j)
        acc[i][j] =
            __builtin_amdgcn_mfma_f32_16x16x32_bf16(af[i], bfr[j], acc[i][j], 0, 0, 0);
  }

  // epilogue: D row = 4*lg + r, col = lr (per 16x16 tile)
#pragma unroll
  for (int j = 0; j < 2; ++j) {
    int c = n0 + 32 * wn + 16 * j + lr;
    float bv = bias[c];
#pragma unroll
    for (int i = 0; i < 2; ++i) {
      int qb = m0 + 32 * wm + 16 * i + 4 * lg; // row for r=0
      if (EPI == 0) {
#pragma unroll
        for (int r = 0; r < 4; ++r)
          O0[(size_t)(qb + r) * 512 + c] = f2bf(acc[i][j][r] + bv);
      } else if (EPI == 2) {
#pragma unroll
        for (int r = 0; r < 4; ++r)
          OF[(size_t)(qb + r) * 512 + c] = acc[i][j][r] + bv;
      } else {
        int b = qb >> 11, s = qb & 2047;
        int hh = c >> 6, hd = c & 63;
        if (z < 2) {
          u16* O = (z == 0) ? O0 : O1;
#pragma unroll
          for (int r = 0; r < 4; ++r)
            O[((size_t)(b * HH + hh) * SS + s + r) * HDD + hd] =
                f2bf(acc[i][j][r] + bv);
        } else {
          ushort4 v;
          v.x = f2bf(acc[i][j][0] + bv);
          v.y = f2bf(acc[i][j][1] + bv);
          v.z = f2bf(acc[i][j][2] + bv);
          v.w = f2bf(acc[i][j][3] + bv);
          *(ushort4*)(O2 + ((size_t)(b * HH + hh) * HDD + hd) * SS + s) = v;
        }
      }
    }
  }
}

// ---------------- flash attention, 8 waves, 2-way KV split --------------------
// grid (32 qtiles, 16 bh), 512 threads. Waves 0-3: q-groups 0-3 x KV[0:1024);
// waves 4-7: same q-groups x KV[1024:2048). Pairwise flash-merge at end via LDS.
__global__ __launch_bounds__(512) void attn2_k(
    const u16* __restrict__ Qh, const u16* __restrict__ Kh,
    const u16* __restrict__ Vt, const float* __restrict__ Mm,
    u16* __restrict__ AO) {
  __shared__ alignas(16) u16 Kl[2][64 * 64];
  __shared__ alignas(16) u16 Vl[2][64 * 64];
  __shared__ alignas(16) u16 Pl[8][16 * 64];

  const int tid = threadIdx.x;
  const int l = tid & 63, w = tid >> 6, lg = l >> 4, lr = l & 15;
  const int qg = w & 3, kh = w >> 2;
  const int bh = blockIdx.y, b = bh >> 3, h = bh & 7;
  const int qw = blockIdx.x * 64 + 16 * qg;

  // Q fragments held in registers (A-frag: row=lr, k=8*lg+j)
  bf16x8 qf[2];
  {
    const u16* qp = Qh + ((size_t)bh * SS + qw + lr) * HDD + 8 * lg;
    qf[0] = *(const bf16x8*)qp;
    qf[1] = *(const bf16x8*)(qp + 32);
  }
  f32x4 zero4 = {0.f, 0.f, 0.f, 0.f};
  f32x4 o[4];
#pragma unroll
  for (int t = 0; t < 4; ++t) o[t] = zero4;
  float mrun[4] = {-INFINITY, -INFINITY, -INFINITY, -INFINITY};
  float lrun[4] = {0.f, 0.f, 0.f, 0.f};

  const float* Mb = Mm + ((size_t)b * SS + qw + 4 * lg) * SS;

  // staging: each thread stages one 16B chunk into each of K0,V0,K1,V1.
  const int srow = tid >> 3;              // 0..63
  const int spos = tid & 7;               // chunk within 128B row
  const int sk8 = spos ^ (srow & 7);      // swizzled source chunk
  const size_t sdst = (size_t)tid * 16;   // linear dest (wave-uniform + lane*16)

  for (int kt = 0; kt < 16; ++kt) {
    const int kb0 = kt * 64, kb1 = 1024 + kt * 64;
    __syncthreads();
    cp16(Kh + ((size_t)bh * SS + kb0 + srow) * HDD + 8 * sk8, (char*)Kl[0] + sdst);
    cp16(Vt + ((size_t)bh * HDD + srow) * SS + kb0 + 8 * sk8, (char*)Vl[0] + sdst);
    cp16(Kh + ((size_t)bh * SS + kb1 + srow) * HDD + 8 * sk8, (char*)Kl[1] + sdst);
    cp16(Vt + ((size_t)bh * HDD + srow) * SS + kb1 + 8 * sk8, (char*)Vl[1] + sdst);
    asm volatile("s_waitcnt vmcnt(0)" ::: "memory");
    __syncthreads();

    const int kb = kh * 1024 + kt * 64;
    const u16* Klw = Kl[kh];
    const u16* Vlw = Vl[kh];

    // QK^T: sc[ct] rows 4lg+r, cols 16ct+lr
    f32x4 sc[4];
#pragma unroll
    for (int ct = 0; ct < 4; ++ct) {
      int krow = 16 * ct + lr;
      const char* kbase = (const char*)Klw + krow * 128;
      bf16x8 k0f = *(const bf16x8*)(kbase + ((lg) ^ (krow & 7)) * 16);
      bf16x8 k1f = *(const bf16x8*)(kbase + ((4 + lg) ^ (krow & 7)) * 16);
      f32x4 zz = zero4;
      zz = __builtin_amdgcn_mfma_f32_16x16x32_bf16(qf[0], k0f, zz, 0, 0, 0);
      zz = __builtin_amdgcn_mfma_f32_16x16x32_bf16(qf[1], k1f, zz, 0, 0, 0);
      sc[ct] = zz;
    }
    // scale + mask
#pragma unroll
    for (int ct = 0; ct < 4; ++ct) {
#pragma unroll
      for (int r = 0; r < 4; ++r) {
        float mv = Mb[(size_t)r * SS + kb + 16 * ct + lr];
        sc[ct][r] = (mv != 0.0f) ? sc[ct][r] * SCALE : -INFINITY;
      }
    }
    // online softmax per accumulator row r (reduce across 16 lr lanes)
#pragma unroll
    for (int r = 0; r < 4; ++r) {
      float t = fmaxf(fmaxf(sc[0][r], sc[1][r]), fmaxf(sc[2][r], sc[3][r]));
      t = fmaxf(t, __shfl_xor(t, 1));
      t = fmaxf(t, __shfl_xor(t, 2));
      t = fmaxf(t, __shfl_xor(t, 4));
      t = fmaxf(t, __shfl_xor(t, 8));
      float mnew = fmaxf(mrun[r], t);
      float fac = (mnew == -INFINITY) ? 1.0f : __expf(mrun[r] - mnew);
      float psum = 0.f;
#pragma unroll
      for (int ct = 0; ct < 4; ++ct) {
        float p = (sc[ct][r] == -INFINITY) ? 0.f : __expf(sc[ct][r] - mnew);
        sc[ct][r] = p;
        psum += p;
      }
      psum += __shfl_xor(psum, 1);
      psum += __shfl_xor(psum, 2);
      psum += __shfl_xor(psum, 4);
      psum += __shfl_xor(psum, 8);
      mrun[r] = mnew;
      lrun[r] = lrun[r] * fac + psum;
#pragma unroll
      for (int t4 = 0; t4 < 4; ++t4) o[t4][r] *= fac;
    }
    // P -> per-wave LDS (bf16, swizzled), then PV
    u16* Pw = Pl[w];
#pragma unroll
    for (int ct = 0; ct < 4; ++ct) {
#pragma unroll
      for (int r = 0; r < 4; ++r) {
        int row = 4 * lg + r;
        int col = 16 * ct + lr;
        int pos = (col >> 3) ^ (row & 7);
        Pw[row * 64 + pos * 8 + (col & 7)] = f2bf(sc[ct][r]);
      }
    }
#pragma unroll
    for (int kk = 0; kk < 2; ++kk) {
      bf16x8 pf = *(const bf16x8*)((const char*)Pw + lr * 128 +
                                   (((4 * kk + lg) ^ (lr & 7)) * 16));
#pragma unroll
      for (int t4 = 0; t4 < 4; ++t4) {
        int vrow = 16 * t4 + lr;
        bf16x8 vf = *(const bf16x8*)((const char*)Vlw + vrow * 128 +
                                     (((4 * kk + lg) ^ (vrow & 7)) * 16));
        o[t4] = __builtin_amdgcn_mfma_f32_16x16x32_bf16(pf, vf, o[t4], 0, 0, 0);
      }
    }
  }

  // pairwise flash-merge: wave w+4 posts partials, wave w merges + stores.
  __syncthreads();
  float* sh = (float*)Kl; // reuse 32KB K/V region (24KB needed)
  if (kh == 1) {
    float* p = sh + ((size_t)(w - 4) * 64 + l) * 24;
#pragma unroll
    for (int r = 0; r < 4; ++r) { p[r] = mrun[r]; p[4 + r] = lrun[r]; }
#pragma unroll
    for (int t4 = 0; t4 < 4; ++t4)
#pragma unroll
      for (int r = 0; r < 4; ++r) p[8 + 4 * t4 + r] = o[t4][r];
  }
  __syncthreads();
  if (kh == 0) {
    const float* p = sh + ((size_t)w * 64 + l) * 24;
#pragma unroll
    for (int r = 0; r < 4; ++r) {
      float mB = p[r], lB = p[4 + r];
      float ms = fmaxf(mrun[r], mB);
      float fa = (mrun[r] > -INFINITY) ? __expf(mrun[r] - ms) : 0.f;
      float fb = (mB > -INFINITY) ? __expf(mB - ms) : 0.f;
      float ls = lrun[r] * fa + lB * fb;
      float inv = (ls > 0.f) ? 1.0f / (ls + 1e-8f) : 0.f;
      size_t row = (size_t)b * SS + qw + 4 * lg + r;
#pragma unroll
      for (int t4 = 0; t4 < 4; ++t4) {
        float ov = o[t4][r] * fa + p[8 + 4 * t4 + r] * fb;
        AO[row * DDIM + h * HDD + 16 * t4 + lr] = f2bf(ov * inv);
      }
    }
  }
}

// ---------------- launcher ----------------
extern "C" void kernel_launch(void* const* d_in, const int* in_sizes, int n_in,
                              void* d_out, int out_size, void* d_ws, size_t ws_size,
                              hipStream_t stream) {
  if (ws_size < (size_t)(31.5 * 1024 * 1024)) return;

  const float* gene = (const float*)d_in[0];
  const float* expr = (const float*)d_in[1];
  const float* Mm = (const float*)d_in[2];
  const float* Wf = (const float*)d_in[3];
  const float* bf = (const float*)d_in[4];
  const float* Wq = (const float*)d_in[5];
  const float* bq = (const float*)d_in[6];
  const float* Wk = (const float*)d_in[7];
  const float* bk = (const float*)d_in[8];
  const float* Wv = (const float*)d_in[9];
  const float* bv = (const float*)d_in[10];
  const float* Wo = (const float*)d_in[11];
  const float* bo = (const float*)d_in[12];
  float* out = (float*)d_out;

  char* ws = (char*)d_ws;
  const size_t MB4 = 4194304; // 4096*512*2 bytes
  u16* geneB = (u16*)(ws + 0 * MB4);
  u16* exprB = (u16*)(ws + 1 * MB4);
  u16* fusedB = (u16*)(ws + 2 * MB4);
  u16* QhB = (u16*)(ws + 3 * MB4);
  u16* KhB = (u16*)(ws + 4 * MB4);
  u16* VtB = (u16*)(ws + 5 * MB4);
  u16* attnB = (u16*)(ws + 6 * MB4);
  u16* WfT = (u16*)(ws + 7 * MB4);
  u16* WqT = (u16*)(ws + 7 * MB4 + 1048576);
  u16* WkT = (u16*)(ws + 7 * MB4 + 1048576 + 524288);
  u16* WvT = (u16*)(ws + 7 * MB4 + 1048576 + 2 * 524288);
  u16* WoT = (u16*)(ws + 7 * MB4 + 1048576 + 3 * 524288);

  cast_bf16_k<<<2048, 256, 0, stream>>>(gene, expr, geneB, exprB);
  wprep_k<<<dim3(16, 32, 5), 256, 0, stream>>>(Wf, Wq, Wk, Wv, Wo, WfT, WqT,
                                               WkT, WvT, WoT);
  gemm_k<0><<<dim3(8, 64), 256, 0, stream>>>(geneB, exprB, WfT, nullptr, nullptr,
                                             bf, nullptr, nullptr, fusedB,
                                             nullptr, nullptr, nullptr);
  gemm_k<1><<<dim3(8, 64, 3), 256, 0, stream>>>(fusedB, exprB, WqT, WkT, WvT,
                                                bq, bk, bv, QhB, KhB, VtB,
                                                nullptr);
  attn2_k<<<dim3(32, 16), 512, 0, stream>>>(QhB, KhB, VtB, Mm, attnB);
  gemm_k<2><<<dim3(8, 64), 256, 0, stream>>>(attnB, nullptr, WoT, nullptr,
                                             nullptr, bo, nullptr, nullptr,
                                             nullptr, nullptr, nullptr, out);
}